// Round 19
// baseline (137.960 us; speedup 1.0000x reference)
//
#include <hip/hip_runtime.h>
#include <hip/hip_bf16.h>

#define HIDDEN 256
#define NB 4            // batches
#define NQ 200          // queries
#define MT 13           // m-tiles of 16 (208 padded rows)
#define HW 65536        // 256*256 pixels
#define KSTEPS 8        // 256 / 32
#define NPB 128         // pixels per gemm tile
#define NTILE 8         // tiles per persistent block (8*128 = 1024 px span)
#define NSLOT 32        // 8 tiles x 4 quarter-k slots
#define GT 512          // gemm threads (8 waves)
#define HBB 16384       // quarter-panel bytes: 128 n x 64 k bf16
#define ABYTES (MT * KSTEPS * 1024)          // 106496: A frags in LDS
#define SMEM_TOTAL (ABYTES + 3 * HBB)        // 155648 <= 160 KB

typedef __attribute__((ext_vector_type(8))) __bf16 bf16x8;
typedef __attribute__((ext_vector_type(4))) float f32x4;

#define WAITVM0()    asm volatile("s_waitcnt vmcnt(0)" ::: "memory")
#define WAIT_LGKM0() asm volatile("s_waitcnt lgkmcnt(0)" ::: "memory")
__device__ __forceinline__ void hard_barrier() {
    __builtin_amdgcn_sched_barrier(0);
    __builtin_amdgcn_s_barrier();
    __builtin_amdgcn_sched_barrier(0);
}

// async global->LDS, 16 B per lane; LDS dest = wave-uniform base + lane*16
__device__ __forceinline__ void gload_lds16(const void* g, void* l) {
    __builtin_amdgcn_global_load_lds(
        (const __attribute__((address_space(1))) void*)g,
        (__attribute__((address_space(3))) void*)l, 16, 0, 0);
}

// ---------------------------------------------------------------------------
// Kernel 1 v17 (r18-verified): mask_embed MLP, 208 blocks, 512 FMA/thread.
// A_ws layout: [b][mt][ks][lane(64)][j(8)] bf16,
//   element (row = mt*16 + (lane&15), k = ks*32 + (lane>>4)*8 + j)
// ---------------------------------------------------------------------------
__global__ __launch_bounds__(1024)
void mlp_pack(const float* __restrict__ queries,
              const float* __restrict__ w1, const float* __restrict__ b1,
              const float* __restrict__ w2, const float* __restrict__ b2,
              __bf16* __restrict__ A_ws)
{
    __shared__ float qh[4][HIDDEN];    // 4 query rows
    __shared__ float hs[4][HIDDEN];    // hidden rows
    __shared__ float wb[HIDDEN][33];   // weight chunk (padded)
    const int blk = blockIdx.x;
    const int b   = blk / (MT * 4);
    const int rem = blk % (MT * 4);
    const int mt  = rem >> 2;
    const int qr  = rem & 3;           // quarter: rows qr*4 .. qr*4+3 of tile
    const int tid = threadIdx.x;
    const int t   = tid & 255;         // output channel
    const int r   = tid >> 8;          // row within quarter (0..3)
    const int row16 = qr * 4 + r;      // row within m-tile
    const int q   = mt * 16 + row16;   // global query row

    qh[r][t] = (q < NQ) ? queries[((size_t)b * NQ + q) * HIDDEN + t] : 0.f;
    __syncthreads();

    const int sr = tid >> 2;           // weight staging: row
    const int si = tid & 3;            // weight staging: which float4

    float h = b1[t];
    for (int cc = 0; cc < 8; ++cc) {
        const float* src = w1 + (size_t)sr * HIDDEN + cc * 32;
        float4 va = *reinterpret_cast<const float4*>(src + si * 4);
        float4 vb = *reinterpret_cast<const float4*>(src + 16 + si * 4);
        wb[sr][si*4+0] = va.x; wb[sr][si*4+1] = va.y;
        wb[sr][si*4+2] = va.z; wb[sr][si*4+3] = va.w;
        wb[sr][16+si*4+0] = vb.x; wb[sr][16+si*4+1] = vb.y;
        wb[sr][16+si*4+2] = vb.z; wb[sr][16+si*4+3] = vb.w;
        __syncthreads();
        #pragma unroll
        for (int cl = 0; cl < 32; ++cl)
            h = fmaf(qh[r][cc * 32 + cl], wb[t][cl], h);
        __syncthreads();
    }
    hs[r][t] = fmaxf(h, 0.f);
    __syncthreads();

    float me = b2[t];
    for (int cc = 0; cc < 8; ++cc) {
        const float* src = w2 + (size_t)sr * HIDDEN + cc * 32;
        float4 va = *reinterpret_cast<const float4*>(src + si * 4);
        float4 vb = *reinterpret_cast<const float4*>(src + 16 + si * 4);
        wb[sr][si*4+0] = va.x; wb[sr][si*4+1] = va.y;
        wb[sr][si*4+2] = va.z; wb[sr][si*4+3] = va.w;
        wb[sr][16+si*4+0] = vb.x; wb[sr][16+si*4+1] = vb.y;
        wb[sr][16+si*4+2] = vb.z; wb[sr][16+si*4+3] = vb.w;
        __syncthreads();
        #pragma unroll
        for (int cl = 0; cl < 32; ++cl)
            me = fmaf(hs[r][cc * 32 + cl], wb[t][cl], me);
        __syncthreads();
    }

    const int ks = t >> 5, g = (t >> 3) & 3, j = t & 7;
    const float vv = (q < NQ) ? me : 0.f;
    const int lane = row16 + 16 * g;
    size_t addr = ((size_t)((b * MT + mt) * KSTEPS + ks)) * 512 + (size_t)lane * 8 + j;
    A_ws[addr] = (__bf16)vv;
}

// ---------------------------------------------------------------------------
// Kernel 2 v18: r14/r18 champion pipeline + r12's DIRECT-store epilogue with
// NONTEMPORAL scalar stores (unbundling r12's two confounded changes):
//  - r12 proved direct-from-acc stores cut profiled gemm 190->157us (removes
//    the per-tile LDS-transpose serialization r13 kept).
//  - r12's replay regression was its OTHER change: plain (non-NT) stores let
//    the 205-MB output stream evict mf from L3 between graph replays.
//  - Here: direct stores, each __builtin_nontemporal_store on float.
// Everything else identical to r18 (152 KB LDS, A in LDS via gload_lds,
// 3x16 KB quarter-panel ring, 512-B page-run LOADV, 1 barrier/slot).
// C/D frag mapping: col = l15 (+f*16), row = lg*4 + r within m-tile.
// ---------------------------------------------------------------------------
__global__ __launch_bounds__(GT)
void mask_gemm(const float* __restrict__ mf,
               const __bf16* __restrict__ A_ws,
               float* __restrict__ out)
{
    extern __shared__ char smem[];
    char* Ar = smem;                   // A fragment region
    char* HB = smem + ABYTES;          // 3 quarter-panel buffers

    const int bid = blockIdx.x;
    const int b   = bid >> 6;                      // 64 blocks per batch
    const int px0 = (bid & 63) * (NTILE * NPB);    // 1024-px contiguous span
    const int tid = threadIdx.x;
    const int ln  = tid & 63, wv = tid >> 6;
    const int l15 = ln & 15,  lg = ln >> 4;
    const bool has2 = (wv + 8) < MT;

    const float*  mfB  = mf  + (size_t)b * HIDDEN * HW;
    const __bf16* Ab   = A_ws + (size_t)b * (MT * KSTEPS * 512);
    float*        outB = out + (size_t)b * NQ * HW;

    // ---- stage A panel into LDS (once): 13 frags per wave, lane-linear ----
    for (int fi = wv; fi < MT * KSTEPS; fi += 8)
        gload_lds16(Ab + (size_t)fi * 512 + (size_t)ln * 8,
                    Ar + fi * 1024 + ln * 16);

    float v[16];   // staging: wave's 8 k-rows x 2 n-halves (k-run layout)

    // issue loads for a slot; j-outer/c-inner -> 512-B page run per row
    #define LOADV(dst, slot)                                                   \
        do {                                                                   \
            const int i_ = (slot) >> 2, kq_ = (slot) & 3;                      \
            const float* src_ = mfB + (size_t)(kq_ * 64 + wv * 8) * HW         \
                                + px0 + i_ * NPB;                              \
            _Pragma("unroll")                                                  \
            for (int j_ = 0; j_ < 8; ++j_)                                     \
                _Pragma("unroll")                                              \
                for (int c_ = 0; c_ < 2; ++c_)                                 \
                    dst[c_ * 8 + j_] =                                         \
                        src_[(size_t)j_ * HW + c_ * 64 + ln];                  \
        } while (0)

    // cvt + swizzled ds_write (k-run u = wv) into quarter-panel `base`
    #define DSWRITE(base, srcv)                                                \
        do {                                                                   \
            _Pragma("unroll")                                                  \
            for (int c_ = 0; c_ < 2; ++c_) {                                   \
                bf16x8 pk_;                                                    \
                _Pragma("unroll")                                              \
                for (int j_ = 0; j_ < 8; ++j_)                                 \
                    pk_[j_] = (__bf16)srcv[c_ * 8 + j_];                       \
                const int n_ = c_ * 64 + ln;                                   \
                *reinterpret_cast<bf16x8*>(                                    \
                    (base) + n_ * 128 + ((wv ^ (n_ & 7)) << 4)) = pk_;         \
            }                                                                  \
        } while (0)

    // ---- prologue ----
    LOADV(v, 0);
    WAITVM0();                          // A gloads + slot-0 reads complete
    DSWRITE(HB, v);
    WAIT_LGKM0();
    hard_barrier();

    f32x4 acc[2][8];
    #pragma unroll
    for (int ii = 0; ii < 2; ++ii)
        #pragma unroll
        for (int f = 0; f < 8; ++f) acc[ii][f] = (f32x4){0.f, 0.f, 0.f, 0.f};

    // ---- slot loop: 32 slots = 8 tiles x 4 quarter-k ----
    for (int s = 0; s < NSLOT; ++s) {
        const int i = s >> 2, kq = s & 3;
        char* bcur = HB + (s % 3) * HBB;
        const bool hn = (s + 1) < NSLOT;

        if (hn) {
            LOADV(v, s + 1);
            __builtin_amdgcn_sched_barrier(0);   // pin issuance before K-loop
        }

        // compute 2 ksteps from bcur (pure LDS + MFMA)
        #pragma unroll
        for (int t = 0; t < 2; ++t) {
            const int t_ = kq * 2 + t;
            bf16x8 a0 = *reinterpret_cast<const bf16x8*>(
                Ar + (wv * KSTEPS + t_) * 1024 + ln * 16);
            bf16x8 a1;
            if (has2)
                a1 = *reinterpret_cast<const bf16x8*>(
                    Ar + ((wv + 8) * KSTEPS + t_) * 1024 + ln * 16);
            #pragma unroll
            for (int f = 0; f < 8; ++f) {
                bf16x8 bf = *reinterpret_cast<const bf16x8*>(
                    bcur + (f * 16 + l15) * 128 + (((t * 4 + lg) ^ (l15 & 7)) << 4));
                acc[0][f] = __builtin_amdgcn_mfma_f32_16x16x32_bf16(
                    a0, bf, acc[0][f], 0, 0, 0);
                if (has2)
                    acc[1][f] = __builtin_amdgcn_mfma_f32_16x16x32_bf16(
                        a1, bf, acc[1][f], 0, 0, 0);
            }
        }

        // ds_write slot s+1 (ring buffer untouched this slot); the compiler's
        // counted vmcnt wait covers only v's loads.
        if (hn)
            DSWRITE(HB + ((s + 1) % 3) * HBB, v);

        // tile end (kq==3): DIRECT nontemporal stores from acc.
        // No LDS, no waits, no barriers: 64 NT dword stores per lane.
        // Adjacent f's (64-B segments, 16 lanes each) land in the same
        // 256-B L2 lines within a few cycles -> write merging; NT keeps
        // the output stream out of L3 (mf residency preserved -- the fix
        // for r12's replay regression).
        if (kq == 3) {
            float* outb = outB + (px0 + i * NPB) + l15;
            #pragma unroll
            for (int ii = 0; ii < 2; ++ii) {
                if (ii == 0 || has2) {
                    const int mt = wv + 8 * ii;
                    #pragma unroll
                    for (int f = 0; f < 8; ++f) {
                        #pragma unroll
                        for (int r = 0; r < 4; ++r) {
                            const int q = mt * 16 + lg * 4 + r;
                            if (q < NQ)
                                __builtin_nontemporal_store(acc[ii][f][r],
                                    outb + (size_t)q * HW + f * 16);
                        }
                    }
                }
            }
            #pragma unroll
            for (int ii = 0; ii < 2; ++ii)
                #pragma unroll
                for (int f = 0; f < 8; ++f)
                    acc[ii][f] = (f32x4){0.f, 0.f, 0.f, 0.f};
        }

        WAIT_LGKM0();
        hard_barrier();                // ds_write visible; bcur reads done
    }
    #undef LOADV
    #undef DSWRITE
}

// ---------------------------------------------------------------------------
extern "C" void kernel_launch(void* const* d_in, const int* in_sizes, int n_in,
                              void* d_out, int out_size, void* d_ws, size_t ws_size,
                              hipStream_t stream)
{
    const float* queries = (const float*)d_in[0];
    const float* mf      = (const float*)d_in[1];
    const float* w1      = (const float*)d_in[2];
    const float* b1      = (const float*)d_in[3];
    const float* w2      = (const float*)d_in[4];
    const float* b2      = (const float*)d_in[5];
    float*  out  = (float*)d_out;
    __bf16* A_ws = (__bf16*)d_ws;   // 4*13*8*512*2 = 425,984 B

    (void)hipFuncSetAttribute((const void*)mask_gemm,
                              hipFuncAttributeMaxDynamicSharedMemorySize,
                              SMEM_TOTAL);

    hipLaunchKernelGGL(mlp_pack, dim3(NB * MT * 4), dim3(1024), 0, stream,
                       queries, w1, b1, w2, b2, A_ws);
    hipLaunchKernelGGL(mask_gemm, dim3(NB * 64), dim3(GT), SMEM_TOTAL, stream,
                       mf, A_ws, out);
}

// Round 20
// 109.145 us; speedup vs baseline: 1.2640x; 1.2640x over previous
//
#include <hip/hip_runtime.h>
#include <hip/hip_bf16.h>

#define HIDDEN 256
#define NB 4            // batches
#define NQ 200          // queries
#define MT 13           // m-tiles of 16 (208 padded rows)
#define HW 65536        // 256*256 pixels
#define KSTEPS 8        // 256 / 32
#define NPB 128         // pixels per gemm tile
#define NTILE 8         // tiles per persistent block (8*128 = 1024 px span)
#define NSLOT 32        // 8 tiles x 4 quarter-k slots
#define GT 512          // gemm threads (8 waves)
#define HBB 16384       // quarter-panel bytes: 128 n x 64 k bf16
#define ABYTES (MT * KSTEPS * 1024)          // 106496: A frags in LDS
#define SMEM_TOTAL (ABYTES + 3 * HBB)        // 155648 <= 160 KB

typedef __attribute__((ext_vector_type(8))) __bf16 bf16x8;
typedef __attribute__((ext_vector_type(4))) float f32x4;

#define WAITVM0()    asm volatile("s_waitcnt vmcnt(0)" ::: "memory")
#define WAIT_LGKM0() asm volatile("s_waitcnt lgkmcnt(0)" ::: "memory")
__device__ __forceinline__ void hard_barrier() {
    __builtin_amdgcn_sched_barrier(0);
    __builtin_amdgcn_s_barrier();
    __builtin_amdgcn_sched_barrier(0);
}

// async global->LDS, 16 B per lane; LDS dest = wave-uniform base + lane*16
__device__ __forceinline__ void gload_lds16(const void* g, void* l) {
    __builtin_amdgcn_global_load_lds(
        (const __attribute__((address_space(1))) void*)g,
        (__attribute__((address_space(3))) void*)l, 16, 0, 0);
}

// ---------------------------------------------------------------------------
// Kernel 1 v17 (r18-verified): mask_embed MLP, 208 blocks, 512 FMA/thread.
// A_ws layout: [b][mt][ks][lane(64)][j(8)] bf16,
//   element (row = mt*16 + (lane&15), k = ks*32 + (lane>>4)*8 + j)
// ---------------------------------------------------------------------------
__global__ __launch_bounds__(1024)
void mlp_pack(const float* __restrict__ queries,
              const float* __restrict__ w1, const float* __restrict__ b1,
              const float* __restrict__ w2, const float* __restrict__ b2,
              __bf16* __restrict__ A_ws)
{
    __shared__ float qh[4][HIDDEN];    // 4 query rows
    __shared__ float hs[4][HIDDEN];    // hidden rows
    __shared__ float wb[HIDDEN][33];   // weight chunk (padded)
    const int blk = blockIdx.x;
    const int b   = blk / (MT * 4);
    const int rem = blk % (MT * 4);
    const int mt  = rem >> 2;
    const int qr  = rem & 3;           // quarter: rows qr*4 .. qr*4+3 of tile
    const int tid = threadIdx.x;
    const int t   = tid & 255;         // output channel
    const int r   = tid >> 8;          // row within quarter (0..3)
    const int row16 = qr * 4 + r;      // row within m-tile
    const int q   = mt * 16 + row16;   // global query row

    qh[r][t] = (q < NQ) ? queries[((size_t)b * NQ + q) * HIDDEN + t] : 0.f;
    __syncthreads();

    const int sr = tid >> 2;           // weight staging: row
    const int si = tid & 3;            // weight staging: which float4

    float h = b1[t];
    for (int cc = 0; cc < 8; ++cc) {
        const float* src = w1 + (size_t)sr * HIDDEN + cc * 32;
        float4 va = *reinterpret_cast<const float4*>(src + si * 4);
        float4 vb = *reinterpret_cast<const float4*>(src + 16 + si * 4);
        wb[sr][si*4+0] = va.x; wb[sr][si*4+1] = va.y;
        wb[sr][si*4+2] = va.z; wb[sr][si*4+3] = va.w;
        wb[sr][16+si*4+0] = vb.x; wb[sr][16+si*4+1] = vb.y;
        wb[sr][16+si*4+2] = vb.z; wb[sr][16+si*4+3] = vb.w;
        __syncthreads();
        #pragma unroll
        for (int cl = 0; cl < 32; ++cl)
            h = fmaf(qh[r][cc * 32 + cl], wb[t][cl], h);
        __syncthreads();
    }
    hs[r][t] = fmaxf(h, 0.f);
    __syncthreads();

    float me = b2[t];
    for (int cc = 0; cc < 8; ++cc) {
        const float* src = w2 + (size_t)sr * HIDDEN + cc * 32;
        float4 va = *reinterpret_cast<const float4*>(src + si * 4);
        float4 vb = *reinterpret_cast<const float4*>(src + 16 + si * 4);
        wb[sr][si*4+0] = va.x; wb[sr][si*4+1] = va.y;
        wb[sr][si*4+2] = va.z; wb[sr][si*4+3] = va.w;
        wb[sr][16+si*4+0] = vb.x; wb[sr][16+si*4+1] = vb.y;
        wb[sr][16+si*4+2] = vb.z; wb[sr][16+si*4+3] = vb.w;
        __syncthreads();
        #pragma unroll
        for (int cl = 0; cl < 32; ++cl)
            me = fmaf(hs[r][cc * 32 + cl], wb[t][cl], me);
        __syncthreads();
    }

    const int ks = t >> 5, g = (t >> 3) & 3, j = t & 7;
    const float vv = (q < NQ) ? me : 0.f;
    const int lane = row16 + 16 * g;
    size_t addr = ((size_t)((b * MT + mt) * KSTEPS + ks)) * 512 + (size_t)lane * 8 + j;
    A_ws[addr] = (__bf16)vv;
}

// ---------------------------------------------------------------------------
// Kernel 2 = r18 CHAMPION, verbatim (109.8 us total).
// Epilogue matrix fully measured (r12/r14/r19): wave-private LDS transpose +
// NT f32x4 256-B stores is the ONLY variant with both full-line L2 write
// merging (WRITE=205MB) and no L3 pollution. Direct NT scalar (r19) skipped
// merging -> WRITE 288MB; direct plain scalar (r12) merged but evicted mf
// from L3 between replays.
// 256 blocks (1/CU), 512 thr / 8 waves, 152 KB LDS:
//   [A frags 104 KB (gload_lds, once)] [3 x 16 KB quarter-panel ring]
// Quarter-panel = 128 n x 64 k bf16. Slot = (tile i = s>>2, kq = s&3).
// Loads: j-outer/c-inner -> 512-B page runs.
// Wave wv owns m-tiles {wv, wv+8} x all 8 n-frags: acc[2][8] = 64 regs.
// Slot s: LOADV(s+1) -> COMPUTE(buf s%3) -> DSWRITE(buf (s+1)%3) ->
//   [kq==3: wave-private epilogue in freed buf (s+2)%3, 512-B NT stores]
//   -> lgkm + barrier.
// Panel elem (n,k): byte n*128 + (((k>>3) ^ (n&7))<<4) + (k&7)*2.
// ---------------------------------------------------------------------------
__global__ __launch_bounds__(GT)
void mask_gemm(const float* __restrict__ mf,
               const __bf16* __restrict__ A_ws,
               float* __restrict__ out)
{
    extern __shared__ char smem[];
    char* Ar = smem;                   // A fragment region
    char* HB = smem + ABYTES;          // 3 quarter-panel buffers

    const int bid = blockIdx.x;
    const int b   = bid >> 6;                      // 64 blocks per batch
    const int px0 = (bid & 63) * (NTILE * NPB);    // 1024-px contiguous span
    const int tid = threadIdx.x;
    const int ln  = tid & 63, wv = tid >> 6;
    const int l15 = ln & 15,  lg = ln >> 4;
    const bool has2 = (wv + 8) < MT;

    const float*  mfB  = mf  + (size_t)b * HIDDEN * HW;
    const __bf16* Ab   = A_ws + (size_t)b * (MT * KSTEPS * 512);
    float*        outB = out + (size_t)b * NQ * HW;

    // ---- stage A panel into LDS (once): 13 frags per wave, lane-linear ----
    for (int fi = wv; fi < MT * KSTEPS; fi += 8)
        gload_lds16(Ab + (size_t)fi * 512 + (size_t)ln * 8,
                    Ar + fi * 1024 + ln * 16);

    float v[16];   // staging: wave's 8 k-rows x 2 n-halves (k-run layout)

    // issue loads for a slot; j-outer/c-inner -> 512-B page run per row
    #define LOADV(dst, slot)                                                   \
        do {                                                                   \
            const int i_ = (slot) >> 2, kq_ = (slot) & 3;                      \
            const float* src_ = mfB + (size_t)(kq_ * 64 + wv * 8) * HW         \
                                + px0 + i_ * NPB;                              \
            _Pragma("unroll")                                                  \
            for (int j_ = 0; j_ < 8; ++j_)                                     \
                _Pragma("unroll")                                              \
                for (int c_ = 0; c_ < 2; ++c_)                                 \
                    dst[c_ * 8 + j_] =                                         \
                        src_[(size_t)j_ * HW + c_ * 64 + ln];                  \
        } while (0)

    // cvt + swizzled ds_write (k-run u = wv) into quarter-panel `base`
    #define DSWRITE(base, srcv)                                                \
        do {                                                                   \
            _Pragma("unroll")                                                  \
            for (int c_ = 0; c_ < 2; ++c_) {                                   \
                bf16x8 pk_;                                                    \
                _Pragma("unroll")                                              \
                for (int j_ = 0; j_ < 8; ++j_)                                 \
                    pk_[j_] = (__bf16)srcv[c_ * 8 + j_];                       \
                const int n_ = c_ * 64 + ln;                                   \
                *reinterpret_cast<bf16x8*>(                                    \
                    (base) + n_ * 128 + ((wv ^ (n_ & 7)) << 4)) = pk_;         \
            }                                                                  \
        } while (0)

    // ---- prologue ----
    LOADV(v, 0);
    WAITVM0();                          // A gloads + slot-0 reads complete
    DSWRITE(HB, v);
    WAIT_LGKM0();
    hard_barrier();

    f32x4 acc[2][8];
    #pragma unroll
    for (int ii = 0; ii < 2; ++ii)
        #pragma unroll
        for (int f = 0; f < 8; ++f) acc[ii][f] = (f32x4){0.f, 0.f, 0.f, 0.f};

    // ---- slot loop: 32 slots = 8 tiles x 4 quarter-k ----
    for (int s = 0; s < NSLOT; ++s) {
        const int i = s >> 2, kq = s & 3;
        char* bcur = HB + (s % 3) * HBB;
        const bool hn = (s + 1) < NSLOT;

        if (hn) {
            LOADV(v, s + 1);
            __builtin_amdgcn_sched_barrier(0);   // pin issuance before K-loop
        }

        // compute 2 ksteps from bcur (pure LDS + MFMA)
        #pragma unroll
        for (int t = 0; t < 2; ++t) {
            const int t_ = kq * 2 + t;
            bf16x8 a0 = *reinterpret_cast<const bf16x8*>(
                Ar + (wv * KSTEPS + t_) * 1024 + ln * 16);
            bf16x8 a1;
            if (has2)
                a1 = *reinterpret_cast<const bf16x8*>(
                    Ar + ((wv + 8) * KSTEPS + t_) * 1024 + ln * 16);
            #pragma unroll
            for (int f = 0; f < 8; ++f) {
                bf16x8 bf = *reinterpret_cast<const bf16x8*>(
                    bcur + (f * 16 + l15) * 128 + (((t * 4 + lg) ^ (l15 & 7)) << 4));
                acc[0][f] = __builtin_amdgcn_mfma_f32_16x16x32_bf16(
                    a0, bf, acc[0][f], 0, 0, 0);
                if (has2)
                    acc[1][f] = __builtin_amdgcn_mfma_f32_16x16x32_bf16(
                        a1, bf, acc[1][f], 0, 0, 0);
            }
        }

        // ds_write slot s+1 (ring buffer untouched this slot); the compiler's
        // counted vmcnt wait covers only v's loads.
        if (hn)
            DSWRITE(HB + ((s + 1) % 3) * HBB, v);

        // tile end (kq==3): wave-private transpose + 512-B NT stores.
        if (kq == 3) {
            float* wscr = reinterpret_cast<float*>(
                HB + ((s + 2) % 3) * HBB + wv * 2048);
            const int n0 = px0 + i * NPB;
            #pragma unroll
            for (int ii = 0; ii < 2; ++ii) {
                if (ii == 0 || has2) {
                    const int mt = wv + 8 * ii;
                    #pragma unroll
                    for (int sp = 0; sp < 4; ++sp) {
                        if (lg == sp) {
                            #pragma unroll
                            for (int f = 0; f < 8; ++f)
                                #pragma unroll
                                for (int r = 0; r < 4; ++r)
                                    wscr[r * 128 + f * 16 + l15] = acc[ii][f][r];
                        }
                        WAIT_LGKM0();            // wave-local: writes visible
                        #pragma unroll
                        for (int rp = 0; rp < 2; ++rp) {
                            const int row = rp * 2 + (ln >> 5);
                            const int c4 = (ln & 31) << 2;
                            f32x4 vv = *reinterpret_cast<const f32x4*>(
                                wscr + row * 128 + c4);
                            const int q = mt * 16 + sp * 4 + row;
                            if (q < NQ)
                                __builtin_nontemporal_store(vv,
                                    reinterpret_cast<f32x4*>(
                                        outB + (size_t)q * HW + n0 + c4));
                        }
                        WAIT_LGKM0();            // reads done before next sp
                    }
                }
            }
            #pragma unroll
            for (int ii = 0; ii < 2; ++ii)
                #pragma unroll
                for (int f = 0; f < 8; ++f)
                    acc[ii][f] = (f32x4){0.f, 0.f, 0.f, 0.f};
        }

        WAIT_LGKM0();
        hard_barrier();                // ds_write visible; bcur reads done
    }
    #undef LOADV
    #undef DSWRITE
}

// ---------------------------------------------------------------------------
extern "C" void kernel_launch(void* const* d_in, const int* in_sizes, int n_in,
                              void* d_out, int out_size, void* d_ws, size_t ws_size,
                              hipStream_t stream)
{
    const float* queries = (const float*)d_in[0];
    const float* mf      = (const float*)d_in[1];
    const float* w1      = (const float*)d_in[2];
    const float* b1      = (const float*)d_in[3];
    const float* w2      = (const float*)d_in[4];
    const float* b2      = (const float*)d_in[5];
    float*  out  = (float*)d_out;
    __bf16* A_ws = (__bf16*)d_ws;   // 4*13*8*512*2 = 425,984 B

    (void)hipFuncSetAttribute((const void*)mask_gemm,
                              hipFuncAttributeMaxDynamicSharedMemorySize,
                              SMEM_TOTAL);

    hipLaunchKernelGGL(mlp_pack, dim3(NB * MT * 4), dim3(1024), 0, stream,
                       queries, w1, b1, w2, b2, A_ws);
    hipLaunchKernelGGL(mask_gemm, dim3(NB * 64), dim3(GT), SMEM_TOTAL, stream,
                       mf, A_ws, out);
}